// Round 4
// baseline (437.873 us; speedup 1.0000x reference)
//
#include <hip/hip_runtime.h>
#include <hip/hip_bf16.h>

#define D 128
#define SLOPE 0.2f

typedef float f4 __attribute__((ext_vector_type(4)));

// ---------- zero fill ----------

__global__ void zero_kernel(int* __restrict__ p, int n) {
  int i = blockIdx.x * blockDim.x + threadIdx.x;
  if (i < n) p[i] = 0;
}

// ---------- counting sort of edges by dst ----------

__global__ void hist_kernel(const int* __restrict__ dst, int* __restrict__ counts, int E) {
  int i = blockIdx.x * blockDim.x + threadIdx.x;
  if (i < E) atomicAdd(&counts[dst[i]], 1);
}

__global__ __launch_bounds__(1024) void scan_kernel(const int* __restrict__ counts,
                                                    int* __restrict__ offsets,
                                                    int* __restrict__ cursor, int n) {
  __shared__ int sums[1024];
  int t = threadIdx.x;
  int per = (n + 1023) >> 10;
  int lo = t * per;
  int hi = lo + per;
  if (lo > n) lo = n;
  if (hi > n) hi = n;
  int s = 0;
  for (int i = lo; i < hi; ++i) s += counts[i];
  sums[t] = s;
  __syncthreads();
  for (int d = 1; d < 1024; d <<= 1) {
    int v = (t >= d) ? sums[t - d] : 0;
    __syncthreads();
    sums[t] += v;
    __syncthreads();
  }
  int excl = (t == 0) ? 0 : sums[t - 1];
  for (int i = lo; i < hi; ++i) {
    offsets[i] = excl;
    cursor[i] = excl;
    excl += counts[i];
  }
  if (t == 1023) offsets[n] = sums[1023];
}

__global__ void scatter_kernel(const int* __restrict__ dst, const int* __restrict__ src,
                               int* __restrict__ cursor, int* __restrict__ perm,
                               int* __restrict__ sperm, int E) {
  int i = blockIdx.x * blockDim.x + threadIdx.x;
  if (i < E) {
    int p = atomicAdd(&cursor[dst[i]], 1);
    perm[p] = i;
    sperm[p] = src[i];
  }
}

// ---------- W transpose ----------

__global__ void transpose_w(const float* __restrict__ Wl, const float* __restrict__ Wr,
                            float* __restrict__ wcatT) {
  int i = blockIdx.x * blockDim.x + threadIdx.x;  // 0..32767
  int k = i >> 8, c = i & 255;
  float v = (c < D) ? Wl[c * D + k] : Wr[(c - D) * D + k];
  wcatT[k * 256 + c] = v;
}

// ---------- f32 GEMM: hl = x@Wl^T + bl, hr = x@Wr^T + br ----------

__global__ __launch_bounds__(256) void gemm_hlr(const float* __restrict__ x,
    const float* __restrict__ wcatT, const float* __restrict__ bl,
    const float* __restrict__ br, float* __restrict__ hl, float* __restrict__ hr,
    int nrows) {
  __shared__ float xs[64 * 128];
  int t = threadIdx.x;
  int row0 = blockIdx.x << 6;
#pragma unroll
  for (int i = 0; i < 8; ++i) {
    int g = t + (i << 8);
    int r = g >> 5, c4 = (g & 31) << 2;
    int gr = row0 + r;
    float4 v = make_float4(0.f, 0.f, 0.f, 0.f);
    if (gr < nrows) v = *(const float4*)(x + (size_t)gr * D + c4);
    *(float4*)(xs + r * 128 + c4) = v;
  }
  __syncthreads();
  int rg = t >> 5, cg = t & 31;
  int r0 = rg << 3, c0 = cg << 3;
  float acc[8][8];
#pragma unroll
  for (int i = 0; i < 8; ++i)
#pragma unroll
    for (int j = 0; j < 8; ++j) acc[i][j] = 0.f;

  for (int kk = 0; kk < 128; kk += 4) {
    float4 xv[8];
#pragma unroll
    for (int i = 0; i < 8; ++i) xv[i] = *(const float4*)(xs + (r0 + i) * 128 + kk);
#pragma unroll
    for (int dk = 0; dk < 4; ++dk) {
      float4 wa = *(const float4*)(wcatT + (kk + dk) * 256 + c0);
      float4 wb = *(const float4*)(wcatT + (kk + dk) * 256 + c0 + 4);
      float wv0 = wa.x, wv1 = wa.y, wv2 = wa.z, wv3 = wa.w;
      float wv4 = wb.x, wv5 = wb.y, wv6 = wb.z, wv7 = wb.w;
#pragma unroll
      for (int i = 0; i < 8; ++i) {
        float xk = (dk == 0) ? xv[i].x : (dk == 1) ? xv[i].y : (dk == 2) ? xv[i].z : xv[i].w;
        acc[i][0] = fmaf(xk, wv0, acc[i][0]);
        acc[i][1] = fmaf(xk, wv1, acc[i][1]);
        acc[i][2] = fmaf(xk, wv2, acc[i][2]);
        acc[i][3] = fmaf(xk, wv3, acc[i][3]);
        acc[i][4] = fmaf(xk, wv4, acc[i][4]);
        acc[i][5] = fmaf(xk, wv5, acc[i][5]);
        acc[i][6] = fmaf(xk, wv6, acc[i][6]);
        acc[i][7] = fmaf(xk, wv7, acc[i][7]);
      }
    }
  }
  float bias[8];
#pragma unroll
  for (int j = 0; j < 8; ++j) bias[j] = (c0 < D) ? bl[c0 + j] : br[c0 - D + j];
#pragma unroll
  for (int i = 0; i < 8; ++i) {
    int gr = row0 + r0 + i;
    if (gr >= nrows) continue;
    float* base = (c0 < D) ? (hl + (size_t)gr * D + c0) : (hr + (size_t)gr * D + (c0 - D));
    float4 o0 = make_float4(acc[i][0] + bias[0], acc[i][1] + bias[1],
                            acc[i][2] + bias[2], acc[i][3] + bias[3]);
    float4 o1 = make_float4(acc[i][4] + bias[4], acc[i][5] + bias[5],
                            acc[i][6] + bias[6], acc[i][7] + bias[7]);
    *(float4*)(base) = o0;
    *(float4*)(base + 4) = o1;
  }
}

// ---------- per-node fused softmax + aggregation ----------
// 1 wave per node; lane = (half = edge parity, l32 = channel/4).
// Each gather instruction fetches TWO full 512B rows (1KB): lanes 0-31 edge i,
// lanes 32-63 edge i+1, float4 (16B) per lane. Halves merged via shfl_xor(32).

__device__ __forceinline__ f4 ld4(const float* p) { return *(const f4*)p; }
__device__ __forceinline__ f4 ld4nt(const float* p) {
  return __builtin_nontemporal_load((const f4*)p);
}

__device__ __forceinline__ f4 escore(f4 h, f4 a, f4 hrv) {
  f4 t = (h + hrv) * a;
#pragma unroll
  for (int k = 0; k < 4; ++k) {
    float tt = t[k];
    tt = (tt >= 0.f) ? tt : SLOPE * tt;
    t[k] = __expf(tt);
  }
  return t;
}

__global__ __launch_bounds__(256) void node_attn(const float* __restrict__ x,
    const float* __restrict__ alpha, const float* __restrict__ hl,
    const float* __restrict__ hr, const int* __restrict__ perm,
    const int* __restrict__ sperm, const int* __restrict__ offsets,
    float* __restrict__ out, int n) {
  int wid = threadIdx.x >> 6, lane = threadIdx.x & 63;
  int v = (blockIdx.x << 2) + wid;
  if (v >= n) return;
  int b = offsets[v], e = offsets[v + 1];
  int half = lane >> 5;
  int ch = (lane & 31) << 2;
  f4 hrv = ld4(hr + (size_t)v * D + ch);
  f4 dx = {0.f, 0.f, 0.f, 0.f};
  f4 ox = {0.f, 0.f, 0.f, 0.f};

  int i = b;
  // main: 4 pairs (8 edges) in flight
  for (; i + 8 <= e; i += 8) {
    int eda[4], ssa[4];
#pragma unroll
    for (int u = 0; u < 4; ++u) {
      int i0 = i + 2 * u;
      int p0 = perm[i0], p1 = perm[i0 + 1];
      int q0 = sperm[i0], q1 = sperm[i0 + 1];
      eda[u] = half ? p1 : p0;
      ssa[u] = half ? q1 : q0;
    }
    f4 av[4], hv[4], xv[4];
#pragma unroll
    for (int u = 0; u < 4; ++u) av[u] = ld4nt(alpha + (size_t)eda[u] * D + ch);
#pragma unroll
    for (int u = 0; u < 4; ++u) hv[u] = ld4(hl + (size_t)ssa[u] * D + ch);
#pragma unroll
    for (int u = 0; u < 4; ++u) xv[u] = ld4(x + (size_t)ssa[u] * D + ch);
#pragma unroll
    for (int u = 0; u < 4; ++u) {
      f4 ev = escore(hv[u], av[u], hrv);
      dx += ev;
      ox += xv[u] * ev;
    }
  }
  // tail: pairs with predication (handles odd count)
  for (; i < e; i += 2) {
    int idx = i + half;
    int j = (idx < e) ? idx : (e - 1);
    int ed = perm[j];
    int ss = sperm[j];
    f4 a = ld4nt(alpha + (size_t)ed * D + ch);
    f4 h = ld4(hl + (size_t)ss * D + ch);
    f4 xw = ld4(x + (size_t)ss * D + ch);
    f4 ev = escore(h, a, hrv);
    float m = (idx < e) ? 1.f : 0.f;
    ev *= m;
    dx += ev;
    ox += xw * ev;
  }
  // merge halves
#pragma unroll
  for (int k = 0; k < 4; ++k) {
    dx[k] += __shfl_xor(dx[k], 32);
    ox[k] += __shfl_xor(ox[k], 32);
  }
  if (half == 0) {
    f4 r;
#pragma unroll
    for (int k = 0; k < 4; ++k) r[k] = (e > b) ? ox[k] / dx[k] : 0.f;
    *(f4*)(out + (size_t)v * D + ch) = r;
  }
}

extern "C" void kernel_launch(void* const* d_in, const int* in_sizes, int n_in,
                              void* d_out, int out_size, void* d_ws, size_t ws_size,
                              hipStream_t stream) {
  const float* x = (const float*)d_in[0];
  const float* alpha = (const float*)d_in[1];
  const float* Wl = (const float*)d_in[2];
  const float* bl = (const float*)d_in[3];
  const float* Wr = (const float*)d_in[4];
  const float* br = (const float*)d_in[5];
  const int* src = (const int*)d_in[6];
  const int* dst = (const int*)d_in[7];
  int N = in_sizes[0] / D;
  int E = in_sizes[6];
  float* out = (float*)d_out;

  char* ws = (char*)d_ws;
  auto al = [](size_t v) { return (v + 255) & ~(size_t)255; };
  size_t off = 0;
  float* hl = (float*)(ws + off); off += al((size_t)N * D * 4);
  float* hr = (float*)(ws + off); off += al((size_t)N * D * 4);
  float* wcatT = (float*)(ws + off); off += al(128 * 256 * 4);
  int* counts = (int*)(ws + off); off += al((size_t)N * 4);
  int* offsets = (int*)(ws + off); off += al((size_t)(N + 1) * 4);
  int* cursor = (int*)(ws + off); off += al((size_t)N * 4);
  int* perm = (int*)(ws + off); off += al((size_t)E * 4);
  int* sperm = (int*)(ws + off); off += al((size_t)E * 4);
  (void)off; (void)ws_size; (void)n_in; (void)out_size;

  const int tb = 256;
  zero_kernel<<<(N + tb - 1) / tb, tb, 0, stream>>>(counts, N);
  hist_kernel<<<(E + tb - 1) / tb, tb, 0, stream>>>(dst, counts, E);
  scan_kernel<<<1, 1024, 0, stream>>>(counts, offsets, cursor, N);
  scatter_kernel<<<(E + tb - 1) / tb, tb, 0, stream>>>(dst, src, cursor, perm, sperm, E);
  transpose_w<<<(128 * 256) / tb, tb, 0, stream>>>(Wl, Wr, wcatT);
  gemm_hlr<<<(N + 63) / 64, 256, 0, stream>>>(x, wcatT, bl, br, hl, hr, N);
  node_attn<<<(N + 3) / 4, 256, 0, stream>>>(x, alpha, hl, hr, perm, sperm, offsets, out, N);
}

// Round 5
// 346.889 us; speedup vs baseline: 1.2623x; 1.2623x over previous
//
#include <hip/hip_runtime.h>
#include <hip/hip_bf16.h>

#define D 128
#define SLOPE 0.2f

typedef float f4 __attribute__((ext_vector_type(4)));

// ---------- zero fill ----------

__global__ void zero_kernel(int* __restrict__ p, int n) {
  int i = blockIdx.x * blockDim.x + threadIdx.x;
  if (i < n) p[i] = 0;
}

// ---------- counting sort of edges by dst ----------

__global__ void hist_kernel(const int* __restrict__ dst, int* __restrict__ counts, int E) {
  int i = blockIdx.x * blockDim.x + threadIdx.x;
  if (i < E) atomicAdd(&counts[dst[i]], 1);
}

// parallel scan: A) per-block inclusive scan, B) one-wave scan of block totals,
// C) fixup to exclusive offsets + cursor.

__global__ __launch_bounds__(1024) void scanA(const int* __restrict__ counts,
                                              int* __restrict__ incl,
                                              int* __restrict__ btot, int n) {
  __shared__ int s[1024];
  int t = threadIdx.x;
  int gid = blockIdx.x * 1024 + t;
  int v = (gid < n) ? counts[gid] : 0;
  s[t] = v;
  __syncthreads();
  for (int d = 1; d < 1024; d <<= 1) {
    int u = (t >= d) ? s[t - d] : 0;
    __syncthreads();
    s[t] += u;
    __syncthreads();
  }
  if (gid < n) incl[gid] = s[t];
  if (t == 1023) btot[blockIdx.x] = s[1023];
}

__global__ void scanB(int* __restrict__ btot, int nb) {
  int l = threadIdx.x & 63;
  int o = (l < nb) ? btot[l] : 0;
  int v = o;
  for (int d = 1; d < 64; d <<= 1) {
    int u = __shfl_up(v, d);
    if (l >= d) v += u;
  }
  if (l < nb) btot[l] = v - o;  // exclusive
}

__global__ __launch_bounds__(1024) void scanC(const int* __restrict__ incl,
                                              const int* __restrict__ counts,
                                              const int* __restrict__ btot,
                                              int* __restrict__ offsets,
                                              int* __restrict__ cursor, int n) {
  int gid = blockIdx.x * 1024 + threadIdx.x;
  if (gid < n) {
    int inc = incl[gid];
    int off = btot[blockIdx.x] + inc - counts[gid];
    offsets[gid] = off;
    cursor[gid] = off;
    if (gid == n - 1) offsets[n] = btot[blockIdx.x] + inc;
  }
}

__global__ void scatter_kernel(const int* __restrict__ dst, const int* __restrict__ src,
                               int* __restrict__ cursor, int2* __restrict__ eperm, int E) {
  int i = blockIdx.x * blockDim.x + threadIdx.x;
  if (i < E) {
    int p = atomicAdd(&cursor[dst[i]], 1);
    int2 v; v.x = i; v.y = src[i];
    eperm[p] = v;
  }
}

// ---------- W transpose ----------

__global__ void transpose_w(const float* __restrict__ Wl, const float* __restrict__ Wr,
                            float* __restrict__ wcatT) {
  int i = blockIdx.x * blockDim.x + threadIdx.x;  // 0..32767
  int k = i >> 8, c = i & 255;
  float v = (c < D) ? Wl[c * D + k] : Wr[(c - D) * D + k];
  wcatT[k * 256 + c] = v;
}

// ---------- f32 GEMM: hx[:,0:128] = x@Wl^T + bl ; hr = x@Wr^T + br ----------
// epilogue also copies the x tile (already staged in LDS) to hx[:,128:256].

__global__ __launch_bounds__(256) void gemm_hlr(const float* __restrict__ x,
    const float* __restrict__ wcatT, const float* __restrict__ bl,
    const float* __restrict__ br, float* __restrict__ hx, float* __restrict__ hr,
    int nrows) {
  __shared__ float xs[64 * 128];
  int t = threadIdx.x;
  int row0 = blockIdx.x << 6;
#pragma unroll
  for (int i = 0; i < 8; ++i) {
    int g = t + (i << 8);
    int r = g >> 5, c4 = (g & 31) << 2;
    int gr = row0 + r;
    float4 v = make_float4(0.f, 0.f, 0.f, 0.f);
    if (gr < nrows) v = *(const float4*)(x + (size_t)gr * D + c4);
    *(float4*)(xs + r * 128 + c4) = v;
  }
  __syncthreads();
  int rg = t >> 5, cg = t & 31;
  int r0 = rg << 3, c0 = cg << 3;
  float acc[8][8];
#pragma unroll
  for (int i = 0; i < 8; ++i)
#pragma unroll
    for (int j = 0; j < 8; ++j) acc[i][j] = 0.f;

  for (int kk = 0; kk < 128; kk += 4) {
    float4 xv[8];
#pragma unroll
    for (int i = 0; i < 8; ++i) xv[i] = *(const float4*)(xs + (r0 + i) * 128 + kk);
#pragma unroll
    for (int dk = 0; dk < 4; ++dk) {
      float4 wa = *(const float4*)(wcatT + (kk + dk) * 256 + c0);
      float4 wb = *(const float4*)(wcatT + (kk + dk) * 256 + c0 + 4);
      float wv0 = wa.x, wv1 = wa.y, wv2 = wa.z, wv3 = wa.w;
      float wv4 = wb.x, wv5 = wb.y, wv6 = wb.z, wv7 = wb.w;
#pragma unroll
      for (int i = 0; i < 8; ++i) {
        float xk = (dk == 0) ? xv[i].x : (dk == 1) ? xv[i].y : (dk == 2) ? xv[i].z : xv[i].w;
        acc[i][0] = fmaf(xk, wv0, acc[i][0]);
        acc[i][1] = fmaf(xk, wv1, acc[i][1]);
        acc[i][2] = fmaf(xk, wv2, acc[i][2]);
        acc[i][3] = fmaf(xk, wv3, acc[i][3]);
        acc[i][4] = fmaf(xk, wv4, acc[i][4]);
        acc[i][5] = fmaf(xk, wv5, acc[i][5]);
        acc[i][6] = fmaf(xk, wv6, acc[i][6]);
        acc[i][7] = fmaf(xk, wv7, acc[i][7]);
      }
    }
  }
  float bias[8];
#pragma unroll
  for (int j = 0; j < 8; ++j) bias[j] = (c0 < D) ? bl[c0 + j] : br[c0 - D + j];
#pragma unroll
  for (int i = 0; i < 8; ++i) {
    int gr = row0 + r0 + i;
    if (gr >= nrows) continue;
    float* base = (c0 < D) ? (hx + (size_t)gr * 256 + c0) : (hr + (size_t)gr * D + (c0 - D));
    float4 o0 = make_float4(acc[i][0] + bias[0], acc[i][1] + bias[1],
                            acc[i][2] + bias[2], acc[i][3] + bias[3]);
    float4 o1 = make_float4(acc[i][4] + bias[4], acc[i][5] + bias[5],
                            acc[i][6] + bias[6], acc[i][7] + bias[7]);
    *(float4*)(base) = o0;
    *(float4*)(base + 4) = o1;
  }
  // copy x tile (in LDS) to hx[:,128:256]
#pragma unroll
  for (int i = 0; i < 8; ++i) {
    int g = t + (i << 8);
    int r = g >> 5, c4 = (g & 31) << 2;
    int gr = row0 + r;
    if (gr < nrows)
      *(float4*)(hx + (size_t)gr * 256 + 128 + c4) = *(const float4*)(xs + r * 128 + c4);
  }
}

// ---------- per-node fused softmax + aggregation ----------
// 1 wave per node; lanes 0-31 edge i, lanes 32-63 edge i+1; float4/lane.
// hx row = [hl(128) | x(128)] so both gathers for src ss land in one 1KB block.

__device__ __forceinline__ f4 ld4(const float* p) { return *(const f4*)p; }
__device__ __forceinline__ f4 ld4nt(const float* p) {
  return __builtin_nontemporal_load((const f4*)p);
}

__device__ __forceinline__ f4 escore(f4 h, f4 a, f4 hrv) {
  f4 t = (h + hrv) * a;
#pragma unroll
  for (int k = 0; k < 4; ++k) {
    float tt = t[k];
    tt = (tt >= 0.f) ? tt : SLOPE * tt;
    t[k] = __expf(tt);
  }
  return t;
}

__global__ __launch_bounds__(256) void node_attn(const float* __restrict__ hx,
    const float* __restrict__ alpha, const float* __restrict__ hr,
    const int2* __restrict__ eperm, const int* __restrict__ offsets,
    float* __restrict__ out, int n) {
  int wid = threadIdx.x >> 6, lane = threadIdx.x & 63;
  int v = (blockIdx.x << 2) + wid;
  if (v >= n) return;
  int b = offsets[v], e = offsets[v + 1];
  int half = lane >> 5;
  int ch = (lane & 31) << 2;
  f4 hrv = ld4(hr + (size_t)v * D + ch);
  f4 dx = {0.f, 0.f, 0.f, 0.f};
  f4 ox = {0.f, 0.f, 0.f, 0.f};

  int i = b;
  for (; i + 8 <= e; i += 8) {
    int eda[4], ssa[4];
#pragma unroll
    for (int u = 0; u < 4; ++u) {
      int i0 = i + 2 * u;
      int2 p0 = eperm[i0], p1 = eperm[i0 + 1];
      eda[u] = half ? p1.x : p0.x;
      ssa[u] = half ? p1.y : p0.y;
    }
    f4 av[4], hv[4], xv[4];
#pragma unroll
    for (int u = 0; u < 4; ++u) av[u] = ld4nt(alpha + (size_t)eda[u] * D + ch);
#pragma unroll
    for (int u = 0; u < 4; ++u) hv[u] = ld4(hx + (size_t)ssa[u] * 256 + ch);
#pragma unroll
    for (int u = 0; u < 4; ++u) xv[u] = ld4(hx + (size_t)ssa[u] * 256 + 128 + ch);
#pragma unroll
    for (int u = 0; u < 4; ++u) {
      f4 ev = escore(hv[u], av[u], hrv);
      dx += ev;
      ox += xv[u] * ev;
    }
  }
  for (; i < e; i += 2) {
    int idx = i + half;
    int j = (idx < e) ? idx : (e - 1);
    int2 pq = eperm[j];
    f4 a = ld4nt(alpha + (size_t)pq.x * D + ch);
    f4 h = ld4(hx + (size_t)pq.y * 256 + ch);
    f4 xw = ld4(hx + (size_t)pq.y * 256 + 128 + ch);
    f4 ev = escore(h, a, hrv);
    float m = (idx < e) ? 1.f : 0.f;
    ev *= m;
    dx += ev;
    ox += xw * ev;
  }
#pragma unroll
  for (int k = 0; k < 4; ++k) {
    dx[k] += __shfl_xor(dx[k], 32);
    ox[k] += __shfl_xor(ox[k], 32);
  }
  if (half == 0) {
    f4 r;
#pragma unroll
    for (int k = 0; k < 4; ++k) r[k] = (e > b) ? ox[k] / dx[k] : 0.f;
    *(f4*)(out + (size_t)v * D + ch) = r;
  }
}

extern "C" void kernel_launch(void* const* d_in, const int* in_sizes, int n_in,
                              void* d_out, int out_size, void* d_ws, size_t ws_size,
                              hipStream_t stream) {
  const float* x = (const float*)d_in[0];
  const float* alpha = (const float*)d_in[1];
  const float* Wl = (const float*)d_in[2];
  const float* bl = (const float*)d_in[3];
  const float* Wr = (const float*)d_in[4];
  const float* br = (const float*)d_in[5];
  const int* src = (const int*)d_in[6];
  const int* dst = (const int*)d_in[7];
  int N = in_sizes[0] / D;
  int E = in_sizes[6];
  float* out = (float*)d_out;

  char* ws = (char*)d_ws;
  auto al = [](size_t v) { return (v + 255) & ~(size_t)255; };
  size_t off = 0;
  float* hx = (float*)(ws + off); off += al((size_t)N * 256 * 4);
  float* hr = (float*)(ws + off); off += al((size_t)N * D * 4);
  float* wcatT = (float*)(ws + off); off += al(128 * 256 * 4);
  int* counts = (int*)(ws + off); off += al((size_t)N * 4);
  int* offsets = (int*)(ws + off); off += al((size_t)(N + 1) * 4);
  int* cursor = (int*)(ws + off); off += al((size_t)N * 4);
  int* incl = (int*)(ws + off); off += al((size_t)N * 4);
  int* btot = (int*)(ws + off); off += al(64 * 4);
  int2* eperm = (int2*)(ws + off); off += al((size_t)E * 8);
  (void)off; (void)ws_size; (void)n_in; (void)out_size;

  const int tb = 256;
  int nb = (N + 1023) / 1024;
  zero_kernel<<<(N + tb - 1) / tb, tb, 0, stream>>>(counts, N);
  hist_kernel<<<(E + tb - 1) / tb, tb, 0, stream>>>(dst, counts, E);
  scanA<<<nb, 1024, 0, stream>>>(counts, incl, btot, N);
  scanB<<<1, 64, 0, stream>>>(btot, nb);
  scanC<<<nb, 1024, 0, stream>>>(incl, counts, btot, offsets, cursor, N);
  scatter_kernel<<<(E + tb - 1) / tb, tb, 0, stream>>>(dst, src, cursor, eperm, E);
  transpose_w<<<(128 * 256) / tb, tb, 0, stream>>>(Wl, Wr, wcatT);
  gemm_hlr<<<(N + 63) / 64, 256, 0, stream>>>(x, wcatT, bl, br, hx, hr, N);
  node_attn<<<(N + 3) / 4, 256, 0, stream>>>(hx, alpha, hr, eperm, offsets, out, N);
}

// Round 7
// 346.727 us; speedup vs baseline: 1.2629x; 1.0005x over previous
//
#include <hip/hip_runtime.h>
#include <hip/hip_bf16.h>

#define D 128
#define SLOPE 0.2f

typedef float f4 __attribute__((ext_vector_type(4)));

// ---------- zero fill ----------

__global__ void zero_kernel(int* __restrict__ p, int n) {
  int i = blockIdx.x * blockDim.x + threadIdx.x;
  if (i < n) p[i] = 0;
}

// ---------- counting sort of edges by dst ----------

__global__ void hist_kernel(const int* __restrict__ dst, int* __restrict__ counts, int E) {
  int i = blockIdx.x * blockDim.x + threadIdx.x;
  if (i < E) atomicAdd(&counts[dst[i]], 1);
}

// parallel scan: A) per-block inclusive scan, B) one-wave scan of block totals,
// C) fixup to exclusive offsets + cursor.

__global__ __launch_bounds__(1024) void scanA(const int* __restrict__ counts,
                                              int* __restrict__ incl,
                                              int* __restrict__ btot, int n) {
  __shared__ int s[1024];
  int t = threadIdx.x;
  int gid = blockIdx.x * 1024 + t;
  int v = (gid < n) ? counts[gid] : 0;
  s[t] = v;
  __syncthreads();
  for (int d = 1; d < 1024; d <<= 1) {
    int u = (t >= d) ? s[t - d] : 0;
    __syncthreads();
    s[t] += u;
    __syncthreads();
  }
  if (gid < n) incl[gid] = s[t];
  if (t == 1023) btot[blockIdx.x] = s[1023];
}

__global__ void scanB(int* __restrict__ btot, int nb) {
  int l = threadIdx.x & 63;
  int o = (l < nb) ? btot[l] : 0;
  int v = o;
  for (int d = 1; d < 64; d <<= 1) {
    int u = __shfl_up(v, d);
    if (l >= d) v += u;
  }
  if (l < nb) btot[l] = v - o;  // exclusive
}

__global__ __launch_bounds__(1024) void scanC(const int* __restrict__ incl,
                                              const int* __restrict__ counts,
                                              const int* __restrict__ btot,
                                              int* __restrict__ offsets,
                                              int* __restrict__ cursor, int n) {
  int gid = blockIdx.x * 1024 + threadIdx.x;
  if (gid < n) {
    int inc = incl[gid];
    int off = btot[blockIdx.x] + inc - counts[gid];
    offsets[gid] = off;
    cursor[gid] = off;
    if (gid == n - 1) offsets[n] = btot[blockIdx.x] + inc;
  }
}

__global__ void scatter_kernel(const int* __restrict__ dst, const int* __restrict__ src,
                               int* __restrict__ cursor, long long* __restrict__ eperm, int E) {
  int i = blockIdx.x * blockDim.x + threadIdx.x;
  if (i < E) {
    int p = atomicAdd(&cursor[dst[i]], 1);
    long long v = (long long)(unsigned int)i | ((long long)src[i] << 32);
    __builtin_nontemporal_store(v, &eperm[p]);
  }
}

// ---------- W transpose ----------

__global__ void transpose_w(const float* __restrict__ Wl, const float* __restrict__ Wr,
                            float* __restrict__ wcatT) {
  int i = blockIdx.x * blockDim.x + threadIdx.x;  // 0..32767
  int k = i >> 8, c = i & 255;
  float v = (c < D) ? Wl[c * D + k] : Wr[(c - D) * D + k];
  wcatT[k * 256 + c] = v;
}

// ---------- f32 GEMM: hx[:,0:128] = x@Wl^T + bl ; hr = x@Wr^T + br ----------
// epilogue also copies the x tile (already staged in LDS) to hx[:,128:256].

__global__ __launch_bounds__(256) void gemm_hlr(const float* __restrict__ x,
    const float* __restrict__ wcatT, const float* __restrict__ bl,
    const float* __restrict__ br, float* __restrict__ hx, float* __restrict__ hr,
    int nrows) {
  __shared__ float xs[64 * 128];
  int t = threadIdx.x;
  int row0 = blockIdx.x << 6;
#pragma unroll
  for (int i = 0; i < 8; ++i) {
    int g = t + (i << 8);
    int r = g >> 5, c4 = (g & 31) << 2;
    int gr = row0 + r;
    float4 v = make_float4(0.f, 0.f, 0.f, 0.f);
    if (gr < nrows) v = *(const float4*)(x + (size_t)gr * D + c4);
    *(float4*)(xs + r * 128 + c4) = v;
  }
  __syncthreads();
  int rg = t >> 5, cg = t & 31;
  int r0 = rg << 3, c0 = cg << 3;
  float acc[8][8];
#pragma unroll
  for (int i = 0; i < 8; ++i)
#pragma unroll
    for (int j = 0; j < 8; ++j) acc[i][j] = 0.f;

  for (int kk = 0; kk < 128; kk += 4) {
    float4 xv[8];
#pragma unroll
    for (int i = 0; i < 8; ++i) xv[i] = *(const float4*)(xs + (r0 + i) * 128 + kk);
#pragma unroll
    for (int dk = 0; dk < 4; ++dk) {
      float4 wa = *(const float4*)(wcatT + (kk + dk) * 256 + c0);
      float4 wb = *(const float4*)(wcatT + (kk + dk) * 256 + c0 + 4);
      float wv0 = wa.x, wv1 = wa.y, wv2 = wa.z, wv3 = wa.w;
      float wv4 = wb.x, wv5 = wb.y, wv6 = wb.z, wv7 = wb.w;
#pragma unroll
      for (int i = 0; i < 8; ++i) {
        float xk = (dk == 0) ? xv[i].x : (dk == 1) ? xv[i].y : (dk == 2) ? xv[i].z : xv[i].w;
        acc[i][0] = fmaf(xk, wv0, acc[i][0]);
        acc[i][1] = fmaf(xk, wv1, acc[i][1]);
        acc[i][2] = fmaf(xk, wv2, acc[i][2]);
        acc[i][3] = fmaf(xk, wv3, acc[i][3]);
        acc[i][4] = fmaf(xk, wv4, acc[i][4]);
        acc[i][5] = fmaf(xk, wv5, acc[i][5]);
        acc[i][6] = fmaf(xk, wv6, acc[i][6]);
        acc[i][7] = fmaf(xk, wv7, acc[i][7]);
      }
    }
  }
  float bias[8];
#pragma unroll
  for (int j = 0; j < 8; ++j) bias[j] = (c0 < D) ? bl[c0 + j] : br[c0 - D + j];
#pragma unroll
  for (int i = 0; i < 8; ++i) {
    int gr = row0 + r0 + i;
    if (gr >= nrows) continue;
    float* base = (c0 < D) ? (hx + (size_t)gr * 256 + c0) : (hr + (size_t)gr * D + (c0 - D));
    float4 o0 = make_float4(acc[i][0] + bias[0], acc[i][1] + bias[1],
                            acc[i][2] + bias[2], acc[i][3] + bias[3]);
    float4 o1 = make_float4(acc[i][4] + bias[4], acc[i][5] + bias[5],
                            acc[i][6] + bias[6], acc[i][7] + bias[7]);
    *(float4*)(base) = o0;
    *(float4*)(base + 4) = o1;
  }
  // copy x tile (in LDS) to hx[:,128:256]
#pragma unroll
  for (int i = 0; i < 8; ++i) {
    int g = t + (i << 8);
    int r = g >> 5, c4 = (g & 31) << 2;
    int gr = row0 + r;
    if (gr < nrows)
      *(float4*)(hx + (size_t)gr * 256 + 128 + c4) = *(const float4*)(xs + r * 128 + c4);
  }
}

// ---------- per-node fused softmax + aggregation ----------
// 1 wave per node; lanes 0-31 edge i, lanes 32-63 edge i+1; float4/lane.
// ALL edges processed in masked 8-edge chunks (no serial tail); indices for
// chunk k+1 prefetched while chunk k's gathers are in flight.

__device__ __forceinline__ f4 ld4(const float* p) { return *(const f4*)p; }
__device__ __forceinline__ f4 ld4nt(const float* p) {
  return __builtin_nontemporal_load((const f4*)p);
}

__device__ __forceinline__ f4 escore(f4 h, f4 a, f4 hrv) {
  f4 t = (h + hrv) * a;
#pragma unroll
  for (int k = 0; k < 4; ++k) {
    float tt = t[k];
    tt = (tt >= 0.f) ? tt : SLOPE * tt;
    t[k] = __expf(tt);
  }
  return t;
}

__global__ __launch_bounds__(256) void node_attn(const float* __restrict__ hx,
    const float* __restrict__ alpha, const float* __restrict__ hr,
    const long long* __restrict__ eperm, const int* __restrict__ offsets,
    float* __restrict__ out, int n) {
  int wid = threadIdx.x >> 6, lane = threadIdx.x & 63;
  int v = (blockIdx.x << 2) + wid;
  if (v >= n) return;
  int b = offsets[v], e = offsets[v + 1];
  int half = lane >> 5;
  int ch = (lane & 31) << 2;

  if (e == b) {
    if (half == 0) {
      f4 z = {0.f, 0.f, 0.f, 0.f};
      *(f4*)(out + (size_t)v * D + ch) = z;
    }
    return;
  }

  f4 hrv = ld4(hr + (size_t)v * D + ch);
  f4 dx = {0.f, 0.f, 0.f, 0.f};
  f4 ox = {0.f, 0.f, 0.f, 0.f};

  int ed[4], ss[4];
  float mk[4];
#define LOADIDX(base, EDA, SSA, MKA)                    \
  {                                                     \
    _Pragma("unroll")                                   \
    for (int u = 0; u < 4; ++u) {                       \
      int idx = (base) + 2 * u + half;                  \
      int j = (idx < e) ? idx : (e - 1);                \
      long long pq = eperm[j];                          \
      EDA[u] = (int)(unsigned int)pq;                   \
      SSA[u] = (int)(pq >> 32);                         \
      MKA[u] = (idx < e) ? 1.f : 0.f;                   \
    }                                                   \
  }

  int i = b;
  LOADIDX(i, ed, ss, mk)
  while (true) {
    // issue all 12 gathers for the current chunk
    f4 av[4], hv[4], xv[4];
#pragma unroll
    for (int u = 0; u < 4; ++u) av[u] = ld4nt(alpha + (size_t)ed[u] * D + ch);
#pragma unroll
    for (int u = 0; u < 4; ++u) hv[u] = ld4(hx + (size_t)ss[u] * 256 + ch);
#pragma unroll
    for (int u = 0; u < 4; ++u) xv[u] = ld4(hx + (size_t)ss[u] * 256 + 128 + ch);

    int inext = i + 8;
    bool more = inext < e;
    int edn[4], ssn[4];
    float mkn[4];
    if (more) LOADIDX(inext, edn, ssn, mkn)  // overlaps gather latency

#pragma unroll
    for (int u = 0; u < 4; ++u) {
      f4 ev = escore(hv[u], av[u], hrv) * mk[u];
      dx += ev;
      ox += xv[u] * ev;
    }
    if (!more) break;
    i = inext;
#pragma unroll
    for (int u = 0; u < 4; ++u) { ed[u] = edn[u]; ss[u] = ssn[u]; mk[u] = mkn[u]; }
  }
#undef LOADIDX

#pragma unroll
  for (int k = 0; k < 4; ++k) {
    dx[k] += __shfl_xor(dx[k], 32);
    ox[k] += __shfl_xor(ox[k], 32);
  }
  if (half == 0) {
    f4 r;
#pragma unroll
    for (int k = 0; k < 4; ++k) r[k] = ox[k] / dx[k];
    *(f4*)(out + (size_t)v * D + ch) = r;
  }
}

extern "C" void kernel_launch(void* const* d_in, const int* in_sizes, int n_in,
                              void* d_out, int out_size, void* d_ws, size_t ws_size,
                              hipStream_t stream) {
  const float* x = (const float*)d_in[0];
  const float* alpha = (const float*)d_in[1];
  const float* Wl = (const float*)d_in[2];
  const float* bl = (const float*)d_in[3];
  const float* Wr = (const float*)d_in[4];
  const float* br = (const float*)d_in[5];
  const int* src = (const int*)d_in[6];
  const int* dst = (const int*)d_in[7];
  int N = in_sizes[0] / D;
  int E = in_sizes[6];
  float* out = (float*)d_out;

  char* ws = (char*)d_ws;
  auto al = [](size_t v) { return (v + 255) & ~(size_t)255; };
  size_t off = 0;
  float* hx = (float*)(ws + off); off += al((size_t)N * 256 * 4);
  float* hr = (float*)(ws + off); off += al((size_t)N * D * 4);
  float* wcatT = (float*)(ws + off); off += al(128 * 256 * 4);
  int* counts = (int*)(ws + off); off += al((size_t)N * 4);
  int* offsets = (int*)(ws + off); off += al((size_t)(N + 1) * 4);
  int* cursor = (int*)(ws + off); off += al((size_t)N * 4);
  int* incl = (int*)(ws + off); off += al((size_t)N * 4);
  int* btot = (int*)(ws + off); off += al(64 * 4);
  long long* eperm = (long long*)(ws + off); off += al((size_t)E * 8);
  (void)off; (void)ws_size; (void)n_in; (void)out_size;

  const int tb = 256;
  int nb = (N + 1023) / 1024;
  zero_kernel<<<(N + tb - 1) / tb, tb, 0, stream>>>(counts, N);
  hist_kernel<<<(E + tb - 1) / tb, tb, 0, stream>>>(dst, counts, E);
  scanA<<<nb, 1024, 0, stream>>>(counts, incl, btot, N);
  scanB<<<1, 64, 0, stream>>>(btot, nb);
  scanC<<<nb, 1024, 0, stream>>>(incl, counts, btot, offsets, cursor, N);
  scatter_kernel<<<(E + tb - 1) / tb, tb, 0, stream>>>(dst, src, cursor, eperm, E);
  transpose_w<<<(128 * 256) / tb, tb, 0, stream>>>(Wl, Wr, wcatT);
  gemm_hlr<<<(N + 63) / 64, 256, 0, stream>>>(x, wcatT, bl, br, hx, hr, N);
  node_attn<<<(N + 3) / 4, 256, 0, stream>>>(hx, alpha, hr, eperm, offsets, out, N);
}